// Round 4
// baseline (42.672 us; speedup 1.0000x reference)
//
#include <hip/hip_runtime.h>

// Fused YOLO target encoder — single kernel, store-first schedule.
//   B=64, O=100, A=9 (3 per layer); layers (128,128,3),(64,64,3),(32,32,3)
//   NSLOT = 49152+12288+3072 = 64512 slots per batch
// Output (flat f32): xcyc[B,NSLOT,2] | wh[B,NSLOT,2] | obj[B,NSLOT] | cls[B,NSLOT] | wt[B,NSLOT,2]
//
// Partition: 1024 blocks = 64 batches x 16 sub-chunks. Sub-chunk r of batch b
// owns slots [r*4032, (r+1)*4032) across ALL five segments, so each block can
// zero its chunk and apply exactly its own records with no cross-block races.
//
// Schedule per block:
//   phase 0: issue zero-fill float4 stores immediately (fire-and-forget)
//   phase 1: compute match + ignore records into LDS (loads overlap store drain)
//   barrier (single vmcnt/lgkm drain)
//   phase 2: merged pokes — ignore(-1) skips any slot present in m_slot[]
//            (match always writes obj=1.0 there, matching reference override);
//            superseded matches skip (survivor writes identical obj).
//            => all phase-2 writes to a given address come from one thread.

namespace {
constexpr int B = 64;
constexpr int O = 100;
constexpr int A = 9;
constexpr int NSLOT = 64512;
constexpr int SUB = 16;                       // sub-chunks per batch
constexpr int SLOT_PER_SUB = NSLOT / SUB;     // 4032
constexpr long long BASE_XCYC = 0;
constexpr long long BASE_WH   = (long long)B * NSLOT * 2;        // 8257536
constexpr long long BASE_OBJ  = BASE_WH * 2;                     // 16515072
constexpr long long BASE_CLS  = BASE_OBJ + (long long)B * NSLOT; // 20643840
constexpr long long BASE_WT   = BASE_CLS + (long long)B * NSLOT; // 24772608
}

__device__ __forceinline__ int layer_offset(int l) {
    return l == 0 ? 0 : (l == 1 ? 49152 : 61440);
}

__global__ __launch_bounds__(256) void encode_fused(
        const int*   __restrict__ matches,
        const float* __restrict__ ious,
        const float* __restrict__ anc0,
        const float* __restrict__ anc1,
        const float* __restrict__ anc2,
        const float* __restrict__ gt_boxes,
        const int*   __restrict__ gt_ids,
        float*       __restrict__ out,
        const int*   __restrict__ in_h_p,
        const int*   __restrict__ in_w_p) {
    __shared__ int   m_slot[O];        // matched slot per object (-1 = none)
    __shared__ float m_val[O][6];      // fx-lx, fy-ly, whx, why, wt, cls
    __shared__ int   ig_slot[A * O];   // ignore slot per (a,o) (-1 = none)

    const int blk = blockIdx.x;
    const int b = blk >> 4;            // batch
    const int r = blk & (SUB - 1);     // sub-chunk
    const int t = threadIdx.x;

    // ---- phase 0: zero this block's chunk FIRST (float4 streaming stores) ----
    const long long fx_base = ((long long)b * NSLOT + (long long)r * SLOT_PER_SUB) * 2;
    const long long s_base  =  (long long)b * NSLOT + (long long)r * SLOT_PER_SUB;
    float4* p_xcyc = (float4*)(out + BASE_XCYC + fx_base);
    float4* p_wh   = (float4*)(out + BASE_WH   + fx_base);
    float4* p_wt   = (float4*)(out + BASE_WT   + fx_base);
    float4* p_obj  = (float4*)(out + BASE_OBJ  + s_base);
    float4* p_cls  = (float4*)(out + BASE_CLS  + s_base);
    const float4 z = make_float4(0.f, 0.f, 0.f, 0.f);
    constexpr int F4_BIG = SLOT_PER_SUB * 2 / 4;   // 2016
    constexpr int F4_SMALL = SLOT_PER_SUB / 4;     // 1008
    for (int i = t; i < F4_BIG; i += 256) { p_xcyc[i] = z; p_wh[i] = z; p_wt[i] = z; }
    for (int i = t; i < F4_SMALL; i += 256) { p_obj[i] = z; p_cls[i] = z; }

    // ---- phase 1: records into LDS (loads overlap the store drain) ----
    const float in_w = (float)in_w_p[0];
    const float in_h = (float)in_h_p[0];

    if (t < O) {
        int m = matches[b * O + t];                // m in [0,9)
        const float* g = gt_boxes + ((long long)b * O + t) * 4;
        float xmin = g[0], ymin = g[1], xmax = g[2], ymax = g[3];
        float w = xmax - xmin, h = ymax - ymin;
        float gtx = (xmin + w) * 0.5f, gty = (ymin + h) * 0.5f;
        bool valid = !((gtx == -1.0f) && (gty == -1.0f) && (w == 0.0f) && (h == 0.0f));

        int layer = m / 3;
        int fw = 128 >> layer;
        int slot = -1;
        float fxr = 0.f, fyr = 0.f, whx = 0.f, why = 0.f, wt = 0.f, cls = 0.f;
        if (valid) {
            float fx = gtx / in_w * (float)fw;
            float fy = gty / in_h * (float)fw;
            int lx = (int)fx, ly = (int)fy;
            int cell = ly * fw + lx;
            if (cell >= 0 && cell < fw * fw) {     // JAX mode='drop'
                slot = layer_offset(layer) + cell * 3 + (m - layer * 3);
                const float* anc = (m < 3) ? anc0 : (m < 6) ? anc1 : anc2;
                int al = m % 3;
                whx = logf(fmaxf(w, 1.0f) / anc[al * 2 + 0]);
                why = logf(fmaxf(h, 1.0f) / anc[al * 2 + 1]);
                wt  = 2.0f - w * h / in_w / in_h;
                cls = (float)gt_ids[b * O + t];
                fxr = fx - (float)lx;
                fyr = fy - (float)ly;
            }
        }
        m_slot[t] = slot;
        m_val[t][0] = fxr; m_val[t][1] = fyr;
        m_val[t][2] = whx; m_val[t][3] = why;
        m_val[t][4] = wt;  m_val[t][5] = cls;
    }

    for (int idx = t; idx < A * O; idx += 256) {
        int a = idx / O;
        int o = idx - a * O;
        float iou = ious[((long long)b * A + a) * O + o];
        int slot = -1;
        if (iou >= 0.5f) {
            const float* g = gt_boxes + ((long long)b * O + o) * 4;
            float xmin = g[0], ymin = g[1], xmax = g[2], ymax = g[3];
            float w = xmax - xmin, h = ymax - ymin;
            float gtx = (xmin + w) * 0.5f, gty = (ymin + h) * 0.5f;
            bool valid = !((gtx == -1.0f) && (gty == -1.0f) && (w == 0.0f) && (h == 0.0f));
            if (valid) {
                int layer = a / 3;
                int fw = 128 >> layer;
                float fx = gtx / in_w * (float)fw;
                float fy = gty / in_h * (float)fw;
                int lx = (int)fx, ly = (int)fy;
                int cell = ly * fw + lx;
                if (cell >= 0 && cell < fw * fw)
                    slot = layer_offset(layer) + cell * 3 + (a - layer * 3);
            }
        }
        ig_slot[idx] = slot;
    }

    __syncthreads();   // single drain: zeros complete + LDS records visible

    // ---- phase 2: merged pokes (disjoint addresses by construction) ----
    const int slot_lo = r * SLOT_PER_SUB;
    const int slot_hi = slot_lo + SLOT_PER_SUB;

    // ignore pokes (obj = -1.0), skipping any slot that a match will claim
    for (int idx = t; idx < A * O; idx += 256) {
        int s = ig_slot[idx];
        if (s >= slot_lo && s < slot_hi) {
            bool is_match = false;
            for (int o = 0; o < O; ++o)
                if (m_slot[o] == s) { is_match = true; break; }
            if (!is_match)
                out[BASE_OBJ + (long long)b * NSLOT + s] = -1.0f;
        }
    }

    // match pokes, numpy last-index-wins (survivor writes everything)
    if (t < O) {
        int s = m_slot[t];
        if (s >= slot_lo && s < slot_hi) {
            bool superseded = false;
            for (int o2 = t + 1; o2 < O; ++o2)
                if (m_slot[o2] == s) { superseded = true; break; }
            if (!superseded) {
                long long bs = (long long)b * NSLOT + s;
                *(float2*)(out + BASE_XCYC + bs * 2) = make_float2(m_val[t][0], m_val[t][1]);
                *(float2*)(out + BASE_WH   + bs * 2) = make_float2(m_val[t][2], m_val[t][3]);
                *(float2*)(out + BASE_WT   + bs * 2) = make_float2(m_val[t][4], m_val[t][4]);
                out[BASE_OBJ + bs] = 1.0f;
                out[BASE_CLS + bs] = m_val[t][5];
            }
        }
    }
}

extern "C" void kernel_launch(void* const* d_in, const int* in_sizes, int n_in,
                              void* d_out, int out_size, void* d_ws, size_t ws_size,
                              hipStream_t stream) {
    const int*   matches  = (const int*)  d_in[0];
    const float* ious     = (const float*)d_in[1];
    // d_in[2..4] = out0/out1/out2 (shape-only, unused)
    const float* anc0     = (const float*)d_in[5];
    const float* anc1     = (const float*)d_in[6];
    const float* anc2     = (const float*)d_in[7];
    const float* gt_boxes = (const float*)d_in[8];
    const int*   gt_ids   = (const int*)  d_in[9];
    const int*   in_h_p   = (const int*)  d_in[10];
    const int*   in_w_p   = (const int*)  d_in[11];
    float* out = (float*)d_out;

    encode_fused<<<B * SUB, 256, 0, stream>>>(matches, ious, anc0, anc1, anc2,
                                              gt_boxes, gt_ids, out, in_h_p, in_w_p);
}

// Round 5
// 34.377 us; speedup vs baseline: 1.2413x; 1.2413x over previous
//
#include <hip/hip_runtime.h>

// Fused YOLO target encoder — single kernel (R2 schedule, SUB=32).
//   B=64, O=100, A=9 (3 per layer); layers (128,128,3),(64,64,3),(32,32,3)
//   NSLOT = 49152+12288+3072 = 64512 slots per batch
// Output (flat f32): xcyc[B,NSLOT,2] | wh[B,NSLOT,2] | obj[B,NSLOT] | cls[B,NSLOT] | wt[B,NSLOT,2]
//
// Partition: 2048 blocks = 64 batches x 32 sub-chunks. Sub-chunk r of batch b
// owns slots [r*2016, (r+1)*2016) across ALL five segments — every float of a
// record with slot s belongs to sub-chunk s/2016, so each block can zero its
// chunk and then apply exactly its own records with no cross-block races.
//
// Schedule per block (R2-proven order):
//   phase 1: record loads -> LDS (issue first; latency hides under store issue)
//   phase 0: zero-fill float4 stores
//   barrier; ignore pokes; barrier; match pokes (last-index-wins via LDS scan)

namespace {
constexpr int B = 64;
constexpr int O = 100;
constexpr int A = 9;
constexpr int NSLOT = 64512;
constexpr int SUB = 32;                       // sub-chunks per batch
constexpr int SLOT_PER_SUB = NSLOT / SUB;     // 2016
constexpr long long BASE_XCYC = 0;
constexpr long long BASE_WH   = (long long)B * NSLOT * 2;        // 8257536
constexpr long long BASE_OBJ  = BASE_WH * 2;                     // 16515072
constexpr long long BASE_CLS  = BASE_OBJ + (long long)B * NSLOT; // 20643840
constexpr long long BASE_WT   = BASE_CLS + (long long)B * NSLOT; // 24772608
}

__device__ __forceinline__ int layer_offset(int l) {
    return l == 0 ? 0 : (l == 1 ? 49152 : 61440);
}

__global__ __launch_bounds__(256) void encode_fused(
        const int*   __restrict__ matches,
        const float* __restrict__ ious,
        const float* __restrict__ anc0,
        const float* __restrict__ anc1,
        const float* __restrict__ anc2,
        const float* __restrict__ gt_boxes,
        const int*   __restrict__ gt_ids,
        float*       __restrict__ out,
        const int*   __restrict__ in_h_p,
        const int*   __restrict__ in_w_p) {
    __shared__ int   m_slot[O];        // matched slot per object (-1 = none)
    __shared__ float m_val[O][6];      // fx-lx, fy-ly, whx, why, wt, cls
    __shared__ int   ig_slot[A * O];   // ignore slot per (a,o) (-1 = none)

    const int blk = blockIdx.x;
    const int b = blk / SUB;           // batch
    const int r = blk % SUB;           // sub-chunk
    const int t = threadIdx.x;

    const float in_w = (float)in_w_p[0];
    const float in_h = (float)in_h_p[0];

    // ---- match records (threads 0..O-1), redundantly per sub-chunk ----
    if (t < O) {
        int m = matches[b * O + t];                // m in [0,9)
        const float* g = gt_boxes + ((long long)b * O + t) * 4;
        float xmin = g[0], ymin = g[1], xmax = g[2], ymax = g[3];
        float w = xmax - xmin, h = ymax - ymin;
        float gtx = (xmin + w) * 0.5f, gty = (ymin + h) * 0.5f;
        bool valid = !((gtx == -1.0f) && (gty == -1.0f) && (w == 0.0f) && (h == 0.0f));

        int layer = m / 3;
        int fw = 128 >> layer;
        int slot = -1;
        float fxr = 0.f, fyr = 0.f, whx = 0.f, why = 0.f, wt = 0.f, cls = 0.f;
        if (valid) {
            float fx = gtx / in_w * (float)fw;
            float fy = gty / in_h * (float)fw;
            int lx = (int)fx, ly = (int)fy;
            int cell = ly * fw + lx;
            if (cell >= 0 && cell < fw * fw) {     // JAX mode='drop'
                slot = layer_offset(layer) + cell * 3 + (m - layer * 3);
                const float* anc = (m < 3) ? anc0 : (m < 6) ? anc1 : anc2;
                int al = m % 3;
                whx = logf(fmaxf(w, 1.0f) / anc[al * 2 + 0]);
                why = logf(fmaxf(h, 1.0f) / anc[al * 2 + 1]);
                wt  = 2.0f - w * h / in_w / in_h;
                cls = (float)gt_ids[b * O + t];
                fxr = fx - (float)lx;
                fyr = fy - (float)ly;
            }
        }
        m_slot[t] = slot;
        m_val[t][0] = fxr; m_val[t][1] = fyr;
        m_val[t][2] = whx; m_val[t][3] = why;
        m_val[t][4] = wt;  m_val[t][5] = cls;
    }

    // ---- ignore records: 900 (a,o) pairs over 256 threads ----
    for (int idx = t; idx < A * O; idx += 256) {
        int a = idx / O;
        int o = idx - a * O;
        float iou = ious[((long long)b * A + a) * O + o];
        int slot = -1;
        if (iou >= 0.5f) {
            const float* g = gt_boxes + ((long long)b * O + o) * 4;
            float xmin = g[0], ymin = g[1], xmax = g[2], ymax = g[3];
        float w = xmax - xmin, h = ymax - ymin;
            float gtx = (xmin + w) * 0.5f, gty = (ymin + h) * 0.5f;
            bool valid = !((gtx == -1.0f) && (gty == -1.0f) && (w == 0.0f) && (h == 0.0f));
            if (valid) {
                int layer = a / 3;
                int fw = 128 >> layer;
                float fx = gtx / in_w * (float)fw;
                float fy = gty / in_h * (float)fw;
                int lx = (int)fx, ly = (int)fy;
                int cell = ly * fw + lx;
                if (cell >= 0 && cell < fw * fw)
                    slot = layer_offset(layer) + cell * 3 + (a - layer * 3);
            }
        }
        ig_slot[idx] = slot;
    }

    // ---- zero this block's chunk (float4 streaming stores) ----
    const long long fx_base = ((long long)b * NSLOT + (long long)r * SLOT_PER_SUB) * 2;
    const long long s_base  =  (long long)b * NSLOT + (long long)r * SLOT_PER_SUB;
    float4* p_xcyc = (float4*)(out + BASE_XCYC + fx_base);
    float4* p_wh   = (float4*)(out + BASE_WH   + fx_base);
    float4* p_wt   = (float4*)(out + BASE_WT   + fx_base);
    float4* p_obj  = (float4*)(out + BASE_OBJ  + s_base);
    float4* p_cls  = (float4*)(out + BASE_CLS  + s_base);
    const float4 z = make_float4(0.f, 0.f, 0.f, 0.f);
    constexpr int F4_BIG = SLOT_PER_SUB * 2 / 4;   // 1008
    constexpr int F4_SMALL = SLOT_PER_SUB / 4;     // 504
    for (int i = t; i < F4_BIG; i += 256) { p_xcyc[i] = z; p_wh[i] = z; p_wt[i] = z; }
    for (int i = t; i < F4_SMALL; i += 256) { p_obj[i] = z; p_cls[i] = z; }

    __syncthreads();   // zeros + LDS records visible block-wide

    // ---- ignore pokes (obj = -1.0), only slots this block owns ----
    const int slot_lo = r * SLOT_PER_SUB;
    const int slot_hi = slot_lo + SLOT_PER_SUB;
    for (int idx = t; idx < A * O; idx += 256) {
        int s = ig_slot[idx];
        if (s >= slot_lo && s < slot_hi)
            out[BASE_OBJ + (long long)b * NSLOT + s] = -1.0f;
    }

    __syncthreads();   // ignore writes land before match overrides

    // ---- match pokes, numpy last-index-wins ----
    if (t < O) {
        int s = m_slot[t];
        if (s >= slot_lo && s < slot_hi) {
            bool superseded = false;
            for (int o2 = t + 1; o2 < O; ++o2)
                if (m_slot[o2] == s) { superseded = true; break; }
            if (!superseded) {
                long long bs = (long long)b * NSLOT + s;
                out[BASE_XCYC + bs * 2 + 0] = m_val[t][0];
                out[BASE_XCYC + bs * 2 + 1] = m_val[t][1];
                out[BASE_WH   + bs * 2 + 0] = m_val[t][2];
                out[BASE_WH   + bs * 2 + 1] = m_val[t][3];
                out[BASE_WT   + bs * 2 + 0] = m_val[t][4];
                out[BASE_WT   + bs * 2 + 1] = m_val[t][4];
                out[BASE_OBJ  + bs] = 1.0f;
                out[BASE_CLS  + bs] = m_val[t][5];
            }
        }
    }
}

extern "C" void kernel_launch(void* const* d_in, const int* in_sizes, int n_in,
                              void* d_out, int out_size, void* d_ws, size_t ws_size,
                              hipStream_t stream) {
    const int*   matches  = (const int*)  d_in[0];
    const float* ious     = (const float*)d_in[1];
    // d_in[2..4] = out0/out1/out2 (shape-only, unused)
    const float* anc0     = (const float*)d_in[5];
    const float* anc1     = (const float*)d_in[6];
    const float* anc2     = (const float*)d_in[7];
    const float* gt_boxes = (const float*)d_in[8];
    const int*   gt_ids   = (const int*)  d_in[9];
    const int*   in_h_p   = (const int*)  d_in[10];
    const int*   in_w_p   = (const int*)  d_in[11];
    float* out = (float*)d_out;

    encode_fused<<<B * SUB, 256, 0, stream>>>(matches, ious, anc0, anc1, anc2,
                                              gt_boxes, gt_ids, out, in_h_p, in_w_p);
}

// Round 6
// 26.998 us; speedup vs baseline: 1.5806x; 1.2733x over previous
//
#include <hip/hip_runtime.h>

// Fused YOLO target encoder — single kernel, compose-on-write (no store drains).
//   B=64, O=100, A=9 (3 per layer); layers (128,128,3),(64,64,3),(32,32,3)
//   NSLOT = 49152+12288+3072 = 64512 slots per batch
// Output (flat f32): xcyc[B,NSLOT,2] | wh[B,NSLOT,2] | obj[B,NSLOT] | cls[B,NSLOT] | wt[B,NSLOT,2]
//
// Partition: 1024 blocks = 64 batches x 16 sub-chunks; sub-chunk owns slots
// [r*4032,(r+1)*4032) across all five segments -> no cross-block races.
//
// Schedule per block:
//   1. init LDS slot table (match idx = -1, ignore bitmap = 0); compute match
//      record values/slots (regs+LDS) and ignore slots (regs). No global stores.
//   2. barrier (LDS-only, cheap)  -> scatter records into table:
//      atomicMax(tbl[slot], o)  == numpy last-index-wins; atomicOr ignore bit.
//   3. barrier (LDS-only, cheap) -> single streaming pass writes every output
//      float EXACTLY ONCE, composing final values from the table. Stores are
//      fire-and-forget; they drain at kernel end like a pure fill kernel.

namespace {
constexpr int B = 64;
constexpr int O = 100;
constexpr int A = 9;
constexpr int NSLOT = 64512;
constexpr int SUB = 16;                       // sub-chunks per batch
constexpr int SPS = NSLOT / SUB;              // 4032 slots per sub-chunk
constexpr long long BASE_XCYC = 0;
constexpr long long BASE_WH   = (long long)B * NSLOT * 2;        // 8257536
constexpr long long BASE_OBJ  = BASE_WH * 2;                     // 16515072
constexpr long long BASE_CLS  = BASE_OBJ + (long long)B * NSLOT; // 20643840
constexpr long long BASE_WT   = BASE_CLS + (long long)B * NSLOT; // 24772608
}

__device__ __forceinline__ int layer_offset(int l) {
    return l == 0 ? 0 : (l == 1 ? 49152 : 61440);
}

__global__ __launch_bounds__(256) void encode_fused(
        const int*   __restrict__ matches,
        const float* __restrict__ ious,
        const float* __restrict__ anc0,
        const float* __restrict__ anc1,
        const float* __restrict__ anc2,
        const float* __restrict__ gt_boxes,
        const int*   __restrict__ gt_ids,
        float*       __restrict__ out,
        const int*   __restrict__ in_h_p,
        const int*   __restrict__ in_w_p) {
    __shared__ int      tbl[SPS];          // last match object idx per rel slot (-1 none)
    __shared__ unsigned ignw[SPS / 32];    // ignore bitmap (126 words)
    __shared__ float    m_val[O][6];       // fx-lx, fy-ly, whx, why, wt, cls

    const int blk = blockIdx.x;
    const int b = blk >> 4;                // batch
    const int r = blk & (SUB - 1);         // sub-chunk
    const int t = threadIdx.x;
    const int lo = r * SPS;
    const int hi = lo + SPS;

    const float in_w = (float)in_w_p[0];
    const float in_h = (float)in_h_p[0];

    // ---- init LDS tables ----
    for (int i = t; i < SPS; i += 256) tbl[i] = -1;
    if (t < SPS / 32) ignw[t] = 0u;

    // ---- match record (threads 0..O-1): values -> LDS, slot -> reg ----
    int m_slot_reg = -1;
    if (t < O) {
        int m = matches[b * O + t];                // m in [0,9)
        const float* g = gt_boxes + ((long long)b * O + t) * 4;
        float xmin = g[0], ymin = g[1], xmax = g[2], ymax = g[3];
        float w = xmax - xmin, h = ymax - ymin;
        float gtx = (xmin + w) * 0.5f, gty = (ymin + h) * 0.5f;
        bool valid = !((gtx == -1.0f) && (gty == -1.0f) && (w == 0.0f) && (h == 0.0f));

        int layer = m / 3;
        int fw = 128 >> layer;
        float fxr = 0.f, fyr = 0.f, whx = 0.f, why = 0.f, wt = 0.f, cls = 0.f;
        if (valid) {
            float fx = gtx / in_w * (float)fw;
            float fy = gty / in_h * (float)fw;
            int lx = (int)fx, ly = (int)fy;
            int cell = ly * fw + lx;
            if (cell >= 0 && cell < fw * fw) {     // JAX mode='drop'
                m_slot_reg = layer_offset(layer) + cell * 3 + (m - layer * 3);
                const float* anc = (m < 3) ? anc0 : (m < 6) ? anc1 : anc2;
                int al = m % 3;
                whx = logf(fmaxf(w, 1.0f) / anc[al * 2 + 0]);
                why = logf(fmaxf(h, 1.0f) / anc[al * 2 + 1]);
                wt  = 2.0f - w * h / in_w / in_h;
                cls = (float)gt_ids[b * O + t];
                fxr = fx - (float)lx;
                fyr = fy - (float)ly;
            }
        }
        m_val[t][0] = fxr; m_val[t][1] = fyr;
        m_val[t][2] = whx; m_val[t][3] = why;
        m_val[t][4] = wt;  m_val[t][5] = cls;
    }

    // ---- ignore slots (4 strided (a,o) pairs per thread) -> regs ----
    int ig_s[4];
#pragma unroll
    for (int k = 0; k < 4; ++k) {
        int idx = t + k * 256;
        int s = -1;
        if (idx < A * O) {
            int a = idx / O;
            int o = idx - a * O;
            float iou = ious[((long long)b * A + a) * O + o];
            if (iou >= 0.5f) {
                const float* g = gt_boxes + ((long long)b * O + o) * 4;
                float xmin = g[0], ymin = g[1], xmax = g[2], ymax = g[3];
                float w = xmax - xmin, h = ymax - ymin;
                float gtx = (xmin + w) * 0.5f, gty = (ymin + h) * 0.5f;
                bool valid = !((gtx == -1.0f) && (gty == -1.0f) && (w == 0.0f) && (h == 0.0f));
                if (valid) {
                    int layer = a / 3;
                    int fw = 128 >> layer;
                    float fx = gtx / in_w * (float)fw;
                    float fy = gty / in_h * (float)fw;
                    int lx = (int)fx, ly = (int)fy;
                    int cell = ly * fw + lx;
                    if (cell >= 0 && cell < fw * fw)
                        s = layer_offset(layer) + cell * 3 + (a - layer * 3);
                }
            }
        }
        ig_s[k] = s;
    }

    __syncthreads();   // LDS init + m_val complete (no global stores in flight)

    // ---- scatter records into slot table ----
    if (m_slot_reg >= lo && m_slot_reg < hi)
        atomicMax(&tbl[m_slot_reg - lo], t);       // last object index wins
#pragma unroll
    for (int k = 0; k < 4; ++k) {
        int s = ig_s[k];
        if (s >= lo && s < hi) {
            int sr = s - lo;
            atomicOr(&ignw[sr >> 5], 1u << (sr & 31));
        }
    }

    __syncthreads();   // table ready (still no global stores in flight)

    // ---- single streaming pass: write every output float exactly once ----
    const long long fx_base = ((long long)b * NSLOT + lo) * 2;
    const long long s_base  =  (long long)b * NSLOT + lo;
    float4* p_xcyc = (float4*)(out + BASE_XCYC + fx_base);
    float4* p_wh   = (float4*)(out + BASE_WH   + fx_base);
    float4* p_wt   = (float4*)(out + BASE_WT   + fx_base);
    float4* p_obj  = (float4*)(out + BASE_OBJ  + s_base);
    float4* p_cls  = (float4*)(out + BASE_CLS  + s_base);
    const float4 z = make_float4(0.f, 0.f, 0.f, 0.f);

    // big segments: window i covers rel slots 2i, 2i+1 (2016 windows)
    for (int i = t; i < SPS * 2 / 4; i += 256) {
        int ia = tbl[2 * i];
        int ib = tbl[2 * i + 1];
        float4 vx = z, vw = z, vt = z;
        if (ia >= 0) {
            vx.x = m_val[ia][0]; vx.y = m_val[ia][1];
            vw.x = m_val[ia][2]; vw.y = m_val[ia][3];
            vt.x = m_val[ia][4]; vt.y = m_val[ia][4];
        }
        if (ib >= 0) {
            vx.z = m_val[ib][0]; vx.w = m_val[ib][1];
            vw.z = m_val[ib][2]; vw.w = m_val[ib][3];
            vt.z = m_val[ib][4]; vt.w = m_val[ib][4];
        }
        p_xcyc[i] = vx;
        p_wh[i]   = vw;
        p_wt[i]   = vt;
    }

    // small segments: window i covers rel slots 4i..4i+3 (1008 windows)
    for (int i = t; i < SPS / 4; i += 256) {
        int s0 = 4 * i;
        unsigned igb = (ignw[s0 >> 5] >> (s0 & 31)) & 0xFu;
        int m0 = tbl[s0], m1 = tbl[s0 + 1], m2 = tbl[s0 + 2], m3 = tbl[s0 + 3];
        float4 vo = z, vc = z;
        if (m0 >= 0) { vo.x = 1.f; vc.x = m_val[m0][5]; } else if (igb & 1u) vo.x = -1.f;
        if (m1 >= 0) { vo.y = 1.f; vc.y = m_val[m1][5]; } else if (igb & 2u) vo.y = -1.f;
        if (m2 >= 0) { vo.z = 1.f; vc.z = m_val[m2][5]; } else if (igb & 4u) vo.z = -1.f;
        if (m3 >= 0) { vo.w = 1.f; vc.w = m_val[m3][5]; } else if (igb & 8u) vo.w = -1.f;
        p_obj[i] = vo;
        p_cls[i] = vc;
    }
}

extern "C" void kernel_launch(void* const* d_in, const int* in_sizes, int n_in,
                              void* d_out, int out_size, void* d_ws, size_t ws_size,
                              hipStream_t stream) {
    const int*   matches  = (const int*)  d_in[0];
    const float* ious     = (const float*)d_in[1];
    // d_in[2..4] = out0/out1/out2 (shape-only, unused)
    const float* anc0     = (const float*)d_in[5];
    const float* anc1     = (const float*)d_in[6];
    const float* anc2     = (const float*)d_in[7];
    const float* gt_boxes = (const float*)d_in[8];
    const int*   gt_ids   = (const int*)  d_in[9];
    const int*   in_h_p   = (const int*)  d_in[10];
    const int*   in_w_p   = (const int*)  d_in[11];
    float* out = (float*)d_out;

    encode_fused<<<B * SUB, 256, 0, stream>>>(matches, ious, anc0, anc1, anc2,
                                              gt_boxes, gt_ids, out, in_h_p, in_w_p);
}

// Round 7
// 25.852 us; speedup vs baseline: 1.6507x; 1.0444x over previous
//
#include <hip/hip_runtime.h>

// Fused YOLO target encoder — single kernel, compose-on-write (no store drains).
//   B=64, O=100, A=9 (3 per layer); layers (128,128,3),(64,64,3),(32,32,3)
//   NSLOT = 49152+12288+3072 = 64512 slots per batch
// Output (flat f32): xcyc[B,NSLOT,2] | wh[B,NSLOT,2] | obj[B,NSLOT] | cls[B,NSLOT] | wt[B,NSLOT,2]
//
// Partition: 1024 blocks = 64 batches x 16 sub-chunks; sub-chunk owns slots
// [r*4032,(r+1)*4032) across all five segments -> no cross-block races.
//
// Schedule per block (all global STORES happen after the last barrier):
//   1. issue iou loads (regs) immediately; threads 0..99 compute per-object
//      records: m_val + per-layer slot bases s_base[o][3] -> LDS; init tbl/ignw.
//   2. LDS-only barrier -> scatter: atomicMax(tbl[slot], o) = numpy
//      last-index-wins; atomicOr ignore bitmap via s_base lookup.
//   3. LDS-only barrier -> compose + stream: every output float written
//      exactly once, fire-and-forget to kernel end (pure-fill behavior).

namespace {
constexpr int B = 64;
constexpr int O = 100;
constexpr int A = 9;
constexpr int NSLOT = 64512;
constexpr int SUB = 16;                       // sub-chunks per batch
constexpr int SPS = NSLOT / SUB;              // 4032 slots per sub-chunk
constexpr long long BASE_XCYC = 0;
constexpr long long BASE_WH   = (long long)B * NSLOT * 2;        // 8257536
constexpr long long BASE_OBJ  = BASE_WH * 2;                     // 16515072
constexpr long long BASE_CLS  = BASE_OBJ + (long long)B * NSLOT; // 20643840
constexpr long long BASE_WT   = BASE_CLS + (long long)B * NSLOT; // 24772608
}

__device__ __forceinline__ int layer_offset(int l) {
    return l == 0 ? 0 : (l == 1 ? 49152 : 61440);
}

__global__ __launch_bounds__(256) void encode_fused(
        const int*   __restrict__ matches,
        const float* __restrict__ ious,
        const float* __restrict__ anc0,
        const float* __restrict__ anc1,
        const float* __restrict__ anc2,
        const float* __restrict__ gt_boxes,
        const int*   __restrict__ gt_ids,
        float*       __restrict__ out,
        const int*   __restrict__ in_h_p,
        const int*   __restrict__ in_w_p) {
    __shared__ int      tbl[SPS];          // last match object idx per rel slot (-1)
    __shared__ unsigned ignw[SPS / 32];    // ignore bitmap (126 words)
    __shared__ float    m_val[O][6];       // fx-lx, fy-ly, whx, why, wt, cls
    __shared__ int      s_base[O][3];      // per-object per-layer slot base (-1)

    const int blk = blockIdx.x;
    const int b = blk >> 4;                // batch
    const int r = blk & (SUB - 1);         // sub-chunk
    const int t = threadIdx.x;
    const int lo = r * SPS;
    const int hi = lo + SPS;

    const float in_w = (float)in_w_p[0];
    const float in_h = (float)in_h_p[0];

    // ---- issue iou loads for this thread's 4 (a,o) pairs immediately ----
    float iou_r[4];
#pragma unroll
    for (int k = 0; k < 4; ++k) {
        int idx = t + k * 256;
        iou_r[k] = (idx < A * O) ? ious[(long long)b * (A * O) + idx] : 0.0f;
    }

    // ---- init LDS tables ----
    for (int i = t; i < SPS; i += 256) tbl[i] = -1;
    if (t < SPS / 32) ignw[t] = 0u;

    // ---- per-object records (threads 0..O-1) ----
    int m_slot_reg = -1;
    if (t < O) {
        int m = matches[b * O + t];                // m in [0,9)
        float4 g = *(const float4*)(gt_boxes + ((long long)b * O + t) * 4);
        float w = g.z - g.x, h = g.w - g.y;
        float gtx = (g.x + w) * 0.5f, gty = (g.y + h) * 0.5f;
        bool valid = !((gtx == -1.0f) && (gty == -1.0f) && (w == 0.0f) && (h == 0.0f));

        int sb_loc[3];
#pragma unroll
        for (int l = 0; l < 3; ++l) {
            int fw = 128 >> l;
            int sb = -1;
            if (valid) {
                float fx = gtx / in_w * (float)fw;
                float fy = gty / in_h * (float)fw;
                int lx = (int)fx, ly = (int)fy;
                int cell = ly * fw + lx;
                if (cell >= 0 && cell < fw * fw)
                    sb = layer_offset(l) + cell * 3;
            }
            sb_loc[l] = sb;
            s_base[t][l] = sb;
        }

        int layer = m / 3;
        float fxr = 0.f, fyr = 0.f, whx = 0.f, why = 0.f, wt = 0.f, cls = 0.f;
        if (sb_loc[layer] >= 0) {
            m_slot_reg = sb_loc[layer] + (m - layer * 3);
            int fw = 128 >> layer;
            float fx = gtx / in_w * (float)fw;
            float fy = gty / in_h * (float)fw;
            int lx = (int)fx, ly = (int)fy;
            const float* anc = (m < 3) ? anc0 : (m < 6) ? anc1 : anc2;
            int al = m % 3;
            whx = logf(fmaxf(w, 1.0f) / anc[al * 2 + 0]);
            why = logf(fmaxf(h, 1.0f) / anc[al * 2 + 1]);
            wt  = 2.0f - w * h / in_w / in_h;
            cls = (float)gt_ids[b * O + t];
            fxr = fx - (float)lx;
            fyr = fy - (float)ly;
        }
        m_val[t][0] = fxr; m_val[t][1] = fyr;
        m_val[t][2] = whx; m_val[t][3] = why;
        m_val[t][4] = wt;  m_val[t][5] = cls;
    }

    __syncthreads();   // LDS init + records visible (no global stores in flight)

    // ---- scatter records into slot table ----
    if (m_slot_reg >= lo && m_slot_reg < hi)
        atomicMax(&tbl[m_slot_reg - lo], t);       // last object index wins
#pragma unroll
    for (int k = 0; k < 4; ++k) {
        int idx = t + k * 256;
        if (idx < A * O && iou_r[k] >= 0.5f) {
            int a = idx / O;
            int o = idx - a * O;
            int l = a / 3;
            int sb = s_base[o][l];
            if (sb >= 0) {
                int s = sb + (a - l * 3);
                if (s >= lo && s < hi) {
                    int sr = s - lo;
                    atomicOr(&ignw[sr >> 5], 1u << (sr & 31));
                }
            }
        }
    }

    __syncthreads();   // table ready (still no global stores in flight)

    // ---- single streaming pass: write every output float exactly once ----
    const long long fx_base = ((long long)b * NSLOT + lo) * 2;
    const long long s_base_g = (long long)b * NSLOT + lo;
    float4* p_xcyc = (float4*)(out + BASE_XCYC + fx_base);
    float4* p_wh   = (float4*)(out + BASE_WH   + fx_base);
    float4* p_wt   = (float4*)(out + BASE_WT   + fx_base);
    float4* p_obj  = (float4*)(out + BASE_OBJ  + s_base_g);
    float4* p_cls  = (float4*)(out + BASE_CLS  + s_base_g);
    const float4 z = make_float4(0.f, 0.f, 0.f, 0.f);

    // big segments: window i covers rel slots 2i, 2i+1 (2016 windows)
#pragma unroll 4
    for (int i = t; i < SPS * 2 / 4; i += 256) {
        int2 pr = *(const int2*)&tbl[2 * i];       // ds_read_b64
        float4 vx = z, vw = z, vt = z;
        if (pr.x >= 0) {
            vx.x = m_val[pr.x][0]; vx.y = m_val[pr.x][1];
            vw.x = m_val[pr.x][2]; vw.y = m_val[pr.x][3];
            vt.x = m_val[pr.x][4]; vt.y = m_val[pr.x][4];
        }
        if (pr.y >= 0) {
            vx.z = m_val[pr.y][0]; vx.w = m_val[pr.y][1];
            vw.z = m_val[pr.y][2]; vw.w = m_val[pr.y][3];
            vt.z = m_val[pr.y][4]; vt.w = m_val[pr.y][4];
        }
        p_xcyc[i] = vx;
        p_wh[i]   = vw;
        p_wt[i]   = vt;
    }

    // small segments: window i covers rel slots 4i..4i+3 (1008 windows)
#pragma unroll 4
    for (int i = t; i < SPS / 4; i += 256) {
        int s0 = 4 * i;
        unsigned igb = (ignw[s0 >> 5] >> (s0 & 31)) & 0xFu;
        int4 mm = *(const int4*)&tbl[s0];          // ds_read_b128
        float4 vo = z, vc = z;
        if (mm.x >= 0) { vo.x = 1.f; vc.x = m_val[mm.x][5]; } else if (igb & 1u) vo.x = -1.f;
        if (mm.y >= 0) { vo.y = 1.f; vc.y = m_val[mm.y][5]; } else if (igb & 2u) vo.y = -1.f;
        if (mm.z >= 0) { vo.z = 1.f; vc.z = m_val[mm.z][5]; } else if (igb & 4u) vo.z = -1.f;
        if (mm.w >= 0) { vo.w = 1.f; vc.w = m_val[mm.w][5]; } else if (igb & 8u) vo.w = -1.f;
        p_obj[i] = vo;
        p_cls[i] = vc;
    }
}

extern "C" void kernel_launch(void* const* d_in, const int* in_sizes, int n_in,
                              void* d_out, int out_size, void* d_ws, size_t ws_size,
                              hipStream_t stream) {
    const int*   matches  = (const int*)  d_in[0];
    const float* ious     = (const float*)d_in[1];
    // d_in[2..4] = out0/out1/out2 (shape-only, unused)
    const float* anc0     = (const float*)d_in[5];
    const float* anc1     = (const float*)d_in[6];
    const float* anc2     = (const float*)d_in[7];
    const float* gt_boxes = (const float*)d_in[8];
    const int*   gt_ids   = (const int*)  d_in[9];
    const int*   in_h_p   = (const int*)  d_in[10];
    const int*   in_w_p   = (const int*)  d_in[11];
    float* out = (float*)d_out;

    encode_fused<<<B * SUB, 256, 0, stream>>>(matches, ious, anc0, anc1, anc2,
                                              gt_boxes, gt_ids, out, in_h_p, in_w_p);
}

// Round 8
// 24.396 us; speedup vs baseline: 1.7492x; 1.0597x over previous
//
#include <hip/hip_runtime.h>

// Fused YOLO target encoder — single kernel, compose-on-write, 512-thread blocks.
//   B=64, O=100, A=9 (3 per layer); layers (128,128,3),(64,64,3),(32,32,3)
//   NSLOT = 49152+12288+3072 = 64512 slots per batch
// Output (flat f32): xcyc[B,NSLOT,2] | wh[B,NSLOT,2] | obj[B,NSLOT] | cls[B,NSLOT] | wt[B,NSLOT,2]
//
// Partition: 1024 blocks = 64 batches x 16 sub-chunks; sub-chunk owns slots
// [r*4032,(r+1)*4032) across all five segments -> no cross-block races.
// 512 threads/block -> 8 waves/block, 4 blocks/CU = 32 waves/CU (max) for
// maximum outstanding-store parallelism on the streaming pass.
//
// Schedule per block (all global STORES happen after the last barrier):
//   1. issue iou float4 loads (threads 0..224) immediately; threads 0..99
//      compute per-object records (m_val + per-layer slot bases) -> LDS;
//      all threads init tbl/ignw.
//   2. LDS-only barrier -> scatter: atomicMax(tbl[slot], o) = numpy
//      last-index-wins; atomicOr ignore bitmap via s_base lookup.
//   3. LDS-only barrier -> compose + stream: every output float written
//      exactly once, fire-and-forget to kernel end (pure-fill behavior).

namespace {
constexpr int B = 64;
constexpr int O = 100;
constexpr int A = 9;
constexpr int NSLOT = 64512;
constexpr int SUB = 16;                       // sub-chunks per batch
constexpr int SPS = NSLOT / SUB;              // 4032 slots per sub-chunk
constexpr int T = 512;                        // threads per block
constexpr long long BASE_XCYC = 0;
constexpr long long BASE_WH   = (long long)B * NSLOT * 2;        // 8257536
constexpr long long BASE_OBJ  = BASE_WH * 2;                     // 16515072
constexpr long long BASE_CLS  = BASE_OBJ + (long long)B * NSLOT; // 20643840
constexpr long long BASE_WT   = BASE_CLS + (long long)B * NSLOT; // 24772608
}

__device__ __forceinline__ int layer_offset(int l) {
    return l == 0 ? 0 : (l == 1 ? 49152 : 61440);
}

__global__ __launch_bounds__(T) void encode_fused(
        const int*   __restrict__ matches,
        const float* __restrict__ ious,
        const float* __restrict__ anc0,
        const float* __restrict__ anc1,
        const float* __restrict__ anc2,
        const float* __restrict__ gt_boxes,
        const int*   __restrict__ gt_ids,
        float*       __restrict__ out,
        const int*   __restrict__ in_h_p,
        const int*   __restrict__ in_w_p) {
    __shared__ int      tbl[SPS];          // last match object idx per rel slot (-1)
    __shared__ unsigned ignw[SPS / 32];    // ignore bitmap (126 words)
    __shared__ float    m_val[O][6];       // fx-lx, fy-ly, whx, why, wt, cls
    __shared__ int      s_base[O][3];      // per-object per-layer slot base (-1)

    const int blk = blockIdx.x;
    const int b = blk >> 4;                // batch
    const int r = blk & (SUB - 1);         // sub-chunk
    const int t = threadIdx.x;
    const int lo = r * SPS;
    const int hi = lo + SPS;

    const float in_w = (float)in_w_p[0];
    const float in_h = (float)in_h_p[0];

    // ---- issue iou loads immediately: threads 0..224 each grab 4 contiguous ----
    float4 iou4 = make_float4(0.f, 0.f, 0.f, 0.f);
    if (t < (A * O) / 4)                       // 225 threads, 900 floats
        iou4 = *(const float4*)(ious + (long long)b * (A * O) + 4 * t);

    // ---- init LDS tables ----
    for (int i = t; i < SPS; i += T) tbl[i] = -1;
    if (t < SPS / 32) ignw[t] = 0u;

    // ---- per-object records (threads 0..O-1) ----
    int m_slot_reg = -1;
    if (t < O) {
        int m = matches[b * O + t];                // m in [0,9)
        float4 g = *(const float4*)(gt_boxes + ((long long)b * O + t) * 4);
        float w = g.z - g.x, h = g.w - g.y;
        float gtx = (g.x + w) * 0.5f, gty = (g.y + h) * 0.5f;
        bool valid = !((gtx == -1.0f) && (gty == -1.0f) && (w == 0.0f) && (h == 0.0f));

        int sb_loc[3];
#pragma unroll
        for (int l = 0; l < 3; ++l) {
            int fw = 128 >> l;
            int sb = -1;
            if (valid) {
                float fx = gtx / in_w * (float)fw;
                float fy = gty / in_h * (float)fw;
                int lx = (int)fx, ly = (int)fy;
                int cell = ly * fw + lx;
                if (cell >= 0 && cell < fw * fw)
                    sb = layer_offset(l) + cell * 3;
            }
            sb_loc[l] = sb;
            s_base[t][l] = sb;
        }

        int layer = m / 3;
        float fxr = 0.f, fyr = 0.f, whx = 0.f, why = 0.f, wt = 0.f, cls = 0.f;
        if (sb_loc[layer] >= 0) {
            m_slot_reg = sb_loc[layer] + (m - layer * 3);
            int fw = 128 >> layer;
            float fx = gtx / in_w * (float)fw;
            float fy = gty / in_h * (float)fw;
            int lx = (int)fx, ly = (int)fy;
            const float* anc = (m < 3) ? anc0 : (m < 6) ? anc1 : anc2;
            int al = m % 3;
            whx = logf(fmaxf(w, 1.0f) / anc[al * 2 + 0]);
            why = logf(fmaxf(h, 1.0f) / anc[al * 2 + 1]);
            wt  = 2.0f - w * h / in_w / in_h;
            cls = (float)gt_ids[b * O + t];
            fxr = fx - (float)lx;
            fyr = fy - (float)ly;
        }
        m_val[t][0] = fxr; m_val[t][1] = fyr;
        m_val[t][2] = whx; m_val[t][3] = why;
        m_val[t][4] = wt;  m_val[t][5] = cls;
    }

    __syncthreads();   // LDS init + records visible (no global stores in flight)

    // ---- scatter records into slot table ----
    if (m_slot_reg >= lo && m_slot_reg < hi)
        atomicMax(&tbl[m_slot_reg - lo], t);       // last object index wins
    if (t < (A * O) / 4) {
        const float iou_k[4] = {iou4.x, iou4.y, iou4.z, iou4.w};
#pragma unroll
        for (int k = 0; k < 4; ++k) {
            if (iou_k[k] >= 0.5f) {
                int idx = 4 * t + k;
                int a = idx / O;
                int o = idx - a * O;
                int l = a / 3;
                int sb = s_base[o][l];
                if (sb >= 0) {
                    int s = sb + (a - l * 3);
                    if (s >= lo && s < hi) {
                        int sr = s - lo;
                        atomicOr(&ignw[sr >> 5], 1u << (sr & 31));
                    }
                }
            }
        }
    }

    __syncthreads();   // table ready (still no global stores in flight)

    // ---- single streaming pass: write every output float exactly once ----
    const long long fx_base = ((long long)b * NSLOT + lo) * 2;
    const long long s_base_g = (long long)b * NSLOT + lo;
    float4* p_xcyc = (float4*)(out + BASE_XCYC + fx_base);
    float4* p_wh   = (float4*)(out + BASE_WH   + fx_base);
    float4* p_wt   = (float4*)(out + BASE_WT   + fx_base);
    float4* p_obj  = (float4*)(out + BASE_OBJ  + s_base_g);
    float4* p_cls  = (float4*)(out + BASE_CLS  + s_base_g);
    const float4 z = make_float4(0.f, 0.f, 0.f, 0.f);

    // big segments: window i covers rel slots 2i, 2i+1 (2016 windows)
#pragma unroll 2
    for (int i = t; i < SPS * 2 / 4; i += T) {
        int2 pr = *(const int2*)&tbl[2 * i];       // ds_read_b64
        float4 vx = z, vw = z, vt = z;
        if (pr.x >= 0) {
            vx.x = m_val[pr.x][0]; vx.y = m_val[pr.x][1];
            vw.x = m_val[pr.x][2]; vw.y = m_val[pr.x][3];
            vt.x = m_val[pr.x][4]; vt.y = m_val[pr.x][4];
        }
        if (pr.y >= 0) {
            vx.z = m_val[pr.y][0]; vx.w = m_val[pr.y][1];
            vw.z = m_val[pr.y][2]; vw.w = m_val[pr.y][3];
            vt.z = m_val[pr.y][4]; vt.w = m_val[pr.y][4];
        }
        p_xcyc[i] = vx;
        p_wh[i]   = vw;
        p_wt[i]   = vt;
    }

    // small segments: window i covers rel slots 4i..4i+3 (1008 windows)
#pragma unroll 2
    for (int i = t; i < SPS / 4; i += T) {
        int s0 = 4 * i;
        unsigned igb = (ignw[s0 >> 5] >> (s0 & 31)) & 0xFu;
        int4 mm = *(const int4*)&tbl[s0];          // ds_read_b128
        float4 vo = z, vc = z;
        if (mm.x >= 0) { vo.x = 1.f; vc.x = m_val[mm.x][5]; } else if (igb & 1u) vo.x = -1.f;
        if (mm.y >= 0) { vo.y = 1.f; vc.y = m_val[mm.y][5]; } else if (igb & 2u) vo.y = -1.f;
        if (mm.z >= 0) { vo.z = 1.f; vc.z = m_val[mm.z][5]; } else if (igb & 4u) vo.z = -1.f;
        if (mm.w >= 0) { vo.w = 1.f; vc.w = m_val[mm.w][5]; } else if (igb & 8u) vo.w = -1.f;
        p_obj[i] = vo;
        p_cls[i] = vc;
    }
}

extern "C" void kernel_launch(void* const* d_in, const int* in_sizes, int n_in,
                              void* d_out, int out_size, void* d_ws, size_t ws_size,
                              hipStream_t stream) {
    const int*   matches  = (const int*)  d_in[0];
    const float* ious     = (const float*)d_in[1];
    // d_in[2..4] = out0/out1/out2 (shape-only, unused)
    const float* anc0     = (const float*)d_in[5];
    const float* anc1     = (const float*)d_in[6];
    const float* anc2     = (const float*)d_in[7];
    const float* gt_boxes = (const float*)d_in[8];
    const int*   gt_ids   = (const int*)  d_in[9];
    const int*   in_h_p   = (const int*)  d_in[10];
    const int*   in_w_p   = (const int*)  d_in[11];
    float* out = (float*)d_out;

    encode_fused<<<B * SUB, T, 0, stream>>>(matches, ious, anc0, anc1, anc2,
                                            gt_boxes, gt_ids, out, in_h_p, in_w_p);
}